// Round 1
// baseline (244.879 us; speedup 1.0000x reference)
//
#include <hip/hip_runtime.h>
#include <stdint.h>

// out[b,s,d] = x[b,s,d] + pe[s,d]   (fp32 in/out)
//   pe[s,d] = (d even) ? sin(s * 10000^(-2d/1024)) : cos(s * 10000^(-2d/1024))
// Shape (8, 4096, 1024). Min traffic: 134 MB read + 134 MB write.
//
// R4 theory: kernel absent from rocprof top-5 (cutoff 79 us) => kernel < 79 us;
// dur_us=230 is dominated by harness re-poison fills. Remaining kernel lever:
// the input is restored right before the timed region => L3(256MiB)-resident.
// NT loads may decline the L3 hit; switch to CACHED loads. Keep NT stores so
// the 134MB output stream does not thrash the 134MB input out of the 256MiB L3
// (268MB combined would not fit).
//
// PE math kept bit-identical to the passing R3 kernel (absmax unchanged).

constexpr int MODEL_DIM = 1024;
constexpr int SEQ = 4096;
constexpr int BATCH = 8;
constexpr int SD = SEQ * MODEL_DIM;           // 4,194,304
constexpr float C_FREQ = -0.025952563241307517f;  // -log2(10000)/512

typedef float v4f __attribute__((ext_vector_type(4)));

__global__ __launch_bounds__(256) void pe_add_kernel(
    const float* __restrict__ xin, float* __restrict__ xout)
{
    const int t = blockIdx.x * blockDim.x + threadIdx.x;  // 0 .. SD/4-1
    const int s = t >> 8;                 // 256 float4 vectors per seq position
    const int dbase = (t & 255) << 2;     // starting dim, multiple of 4 (even)

    const float pos = (float)s;
    float pe[4];
#pragma unroll
    for (int j = 0; j < 4; ++j) {
        const float angle = pos * exp2f(C_FREQ * (float)(dbase + j));
        pe[j] = (j & 1) ? cosf(angle) : sinf(angle);  // accurate range reduction
    }
    v4f pv;
    pv.x = pe[0]; pv.y = pe[1]; pv.z = pe[2]; pv.w = pe[3];

    const size_t base = (size_t)t * 4;
#pragma unroll
    for (int b = 0; b < BATCH; ++b) {
        const size_t off = (size_t)b * (size_t)SD + base;
        v4f x = *(const v4f*)(xin + off);                    // cached: L3-resident input
        x += pv;
        __builtin_nontemporal_store(x, (v4f*)(xout + off));  // write-only stream
    }
}

extern "C" void kernel_launch(void* const* d_in, const int* in_sizes, int n_in,
                              void* d_out, int out_size, void* d_ws, size_t ws_size,
                              hipStream_t stream) {
    const float* x = (const float*)d_in[0];
    float* out = (float*)d_out;
    const int threads = 256;
    const int blocks = (SD / 4) / threads;   // 4096 blocks, exact cover
    pe_add_kernel<<<blocks, threads, 0, stream>>>(x, out);
}

// Round 2
// 243.261 us; speedup vs baseline: 1.0067x; 1.0067x over previous
//
#include <hip/hip_runtime.h>
#include <stdint.h>

// out[b,s,d] = x[b,s,d] + pe[s,d]   (fp32 in/out)
//   pe[s,d] = (d even) ? sin(s * 10000^(-2d/1024)) : cos(s * 10000^(-2d/1024))
// Shape (8, 4096, 1024). Min traffic: 134 MB read + 134 MB write.
//
// R1 post-mortem: load->add->store per batch iter at VGPR_Count=32 means the
// compiler reused registers, and in-order vmcnt retirement coupled every load's
// consumption to the PREVIOUS NT store's drain -> 8 serialized round-trips/wave,
// 1.9 TB/s (23% peak), 106 us. Fix: split phases. Issue all 8 batch loads into
// a register array first (loads-only vmcnt chain, 8x MLP), compute PE while
// they're in flight, then add+store. Stores fire-and-forget until kernel end.
//
// Load policy: cached (R1 proved L3 serves half the input: FETCH 67 MB).
// Store policy: nontemporal (write-once stream; don't thrash input out of L3).
// PE math bit-identical to the passing kernel (absmax unchanged).

constexpr int MODEL_DIM = 1024;
constexpr int SEQ = 4096;
constexpr int BATCH = 8;
constexpr int SD = SEQ * MODEL_DIM;           // 4,194,304
constexpr float C_FREQ = -0.025952563241307517f;  // -log2(10000)/512

typedef float v4f __attribute__((ext_vector_type(4)));

__global__ __launch_bounds__(256) void pe_add_kernel(
    const float* __restrict__ xin, float* __restrict__ xout)
{
    const int t = blockIdx.x * blockDim.x + threadIdx.x;  // 0 .. SD/4-1
    const int s = t >> 8;                 // 256 float4 vectors per seq position
    const int dbase = (t & 255) << 2;     // starting dim, multiple of 4 (even)

    const size_t base = (size_t)t * 4;

    // Phase 1: issue ALL batch loads back-to-back (8 outstanding, loads-only
    // vmcnt chain — no store coupling).
    v4f x[BATCH];
#pragma unroll
    for (int b = 0; b < BATCH; ++b)
        x[b] = *(const v4f*)(xin + (size_t)b * (size_t)SD + base);

    // Phase 2: PE compute overlaps with the loads in flight.
    const float pos = (float)s;
    float pe[4];
#pragma unroll
    for (int j = 0; j < 4; ++j) {
        const float angle = pos * exp2f(C_FREQ * (float)(dbase + j));
        pe[j] = (j & 1) ? cosf(angle) : sinf(angle);  // accurate range reduction
    }
    v4f pv;
    pv.x = pe[0]; pv.y = pe[1]; pv.z = pe[2]; pv.w = pe[3];

    // Phase 3: add + store. Stores drain asynchronously until kernel end.
#pragma unroll
    for (int b = 0; b < BATCH; ++b) {
        v4f y = x[b] + pv;
        __builtin_nontemporal_store(y, (v4f*)(xout + (size_t)b * (size_t)SD + base));
    }
}

extern "C" void kernel_launch(void* const* d_in, const int* in_sizes, int n_in,
                              void* d_out, int out_size, void* d_ws, size_t ws_size,
                              hipStream_t stream) {
    const float* x = (const float*)d_in[0];
    float* out = (float*)d_out;
    const int threads = 256;
    const int blocks = (SD / 4) / threads;   // 4096 blocks, exact cover
    pe_add_kernel<<<blocks, threads, 0, stream>>>(x, out);
}